// Round 3
// baseline (899.955 us; speedup 1.0000x reference)
//
#include <hip/hip_runtime.h>

#define B_ 128
#define T_ 128
#define I_ 1024
#define O_ 1024
#define M_ (B_*T_)          // 16384 rows of h
#define NOUT (M_*O_)        // 16777216 spike outputs, loss at index NOUT

// async global->LDS, 16B per lane. LDS dest must be wave-uniform base + lane*16,
// which our tid*16 slot mapping satisfies.
__device__ __forceinline__ void gld_lds16(const float* g, float* l) {
    __builtin_amdgcn_global_load_lds((const __attribute__((address_space(1))) void*)g,
                                     (__attribute__((address_space(3))) void*)l,
                                     16, 0, 0);
}

// ---------------------------------------------------------------------------
// h = x @ w   (A: [M,K] row-major, B: [K,N] row-major, C: [M,N])
// 128x128 tile, KT=16, 256 threads, 8x8 micro-tile.
// Double-buffered LDS filled by global_load_lds (no VGPR round-trip):
//   per tile: issue 4 DMAs into buf[nxt]; compute buf[cur]; one barrier.
// The s_waitcnt vmcnt(0) the compiler puts before s_barrier is the DMA drain;
// the DMAs get a whole tile's FMA work (~2k cycles) to complete, so it's ~free.
// A stored untransposed [128][16]; per-thread k-group order rotated by ty to
// kill the 4-way bank conflict on A-fragment reads (changes only per-thread
// FP summation order).
// Regs: a 32 + b 8 + acc 64 (AGPR) + addr ~14 -> cap 128 via launch_bounds.
// ---------------------------------------------------------------------------
__global__ __launch_bounds__(256, 4) void gemm_xw(const float* __restrict__ A,
                                                  const float* __restrict__ Bw,
                                                  float* __restrict__ C) {
    const int K = I_, N = O_;
    const int NT = K / 16;
    __shared__ float As2[2][128][16];   // [buf][row][k]  8 KB per buf
    __shared__ float Bs[2][16][128];    // [buf][k][col]  8 KB per buf

    const int tid = threadIdx.x;
    const int tx = tid & 15, ty = tid >> 4;
    const int bm = blockIdx.x * 128, bn = blockIdx.y * 128;

    // DMA source/dest: thread t covers 16B; LDS slot = t*16 bytes in each quarter
    const float* gA = A + (size_t)(bm + (tid >> 2)) * K + ((tid & 3) << 2);
    const float* gB = Bw + (size_t)(tid >> 5) * N + bn + ((tid & 31) << 2);
    float* lA = (float*)As2 + tid * 4;   // As2[0][tid>>2][(tid&3)*4]
    float* lB = (float*)Bs + tid * 4;    // Bs[0][tid>>5][(tid&31)*4]

    float acc[2][2][4][4];
#pragma unroll
    for (int i = 0; i < 2; i++)
#pragma unroll
        for (int j = 0; j < 2; j++)
#pragma unroll
            for (int m = 0; m < 4; m++)
#pragma unroll
                for (int n = 0; n < 4; n++) acc[i][j][m][n] = 0.f;

    // stage tile 0 into buf 0
    {
        gld_lds16(gA, lA);
        gld_lds16(gA + (size_t)64 * K, lA + 1024);       // rows 64..127
        gld_lds16(gB, lB);
        gld_lds16(gB + (size_t)8 * N, lB + 1024);        // k-rows 8..15
    }
    __syncthreads();

    for (int t = 0; t < NT; ++t) {
        const int cur = t & 1;
        if (t + 1 < NT) {
            const int nxt = cur ^ 1;
            const float* a0 = gA + (t + 1) * 16;
            const float* b0 = gB + (size_t)(t + 1) * 16 * N;
            float* la = lA + nxt * 2048;
            float* lb = lB + nxt * 2048;
            gld_lds16(a0, la);
            gld_lds16(a0 + (size_t)64 * K, la + 1024);
            gld_lds16(b0, lb);
            gld_lds16(b0 + (size_t)8 * N, lb + 1024);
        }
        const float* Ab = (const float*)As2 + cur * 2048;
        const float* Bb = (const float*)Bs + cur * 2048;
#pragma unroll
        for (int kg = 0; kg < 4; ++kg) {
            const int kgp = (kg + ty) & 3;               // bank-conflict rotation
            float a[8][4];
#pragma unroll
            for (int r = 0; r < 4; ++r) {
                float4 v0 = *(const float4*)(Ab + (ty * 4 + r) * 16 + kgp * 4);
                float4 v1 = *(const float4*)(Ab + (64 + ty * 4 + r) * 16 + kgp * 4);
                a[r][0] = v0.x; a[r][1] = v0.y; a[r][2] = v0.z; a[r][3] = v0.w;
                a[4 + r][0] = v1.x; a[4 + r][1] = v1.y; a[4 + r][2] = v1.z; a[4 + r][3] = v1.w;
            }
#pragma unroll
            for (int kk = 0; kk < 4; ++kk) {
                const int k = kgp * 4 + kk;
                float4 bv0 = *(const float4*)(Bb + k * 128 + tx * 4);
                float4 bv1 = *(const float4*)(Bb + k * 128 + 64 + tx * 4);
                float bb[8] = {bv0.x, bv0.y, bv0.z, bv0.w,
                               bv1.x, bv1.y, bv1.z, bv1.w};
#pragma unroll
                for (int mi = 0; mi < 2; mi++)
#pragma unroll
                    for (int ni = 0; ni < 2; ni++)
#pragma unroll
                        for (int mm = 0; mm < 4; mm++)
#pragma unroll
                            for (int nn = 0; nn < 4; nn++)
                                acc[mi][ni][mm][nn] += a[mi * 4 + mm][kk] * bb[ni * 4 + nn];
            }
        }
        __syncthreads();
    }

#pragma unroll
    for (int mi = 0; mi < 2; mi++)
#pragma unroll
        for (int mm = 0; mm < 4; mm++) {
            int m = bm + mi * 64 + ty * 4 + mm;
#pragma unroll
            for (int ni = 0; ni < 2; ni++) {
                float4 v = make_float4(acc[mi][ni][mm][0], acc[mi][ni][mm][1],
                                       acc[mi][ni][mm][2], acc[mi][ni][mm][3]);
                *(float4*)(C + (size_t)m * N + bn + ni * 64 + tx * 4) = v;
            }
        }
}

// ---------------------------------------------------------------------------
// d = w^T w   (w: [K=I_, N=O_] row-major). 64x64 tile, KT=32, 256 threads.
// ---------------------------------------------------------------------------
__global__ __launch_bounds__(256) void gemm_wtw(const float* __restrict__ W,
                                                float* __restrict__ D) {
    const int K = I_, N = O_;
    __shared__ float As[32][68];
    __shared__ float Bs[32][68];
    const int tid = threadIdx.x;
    const int tx = tid & 15, ty = tid >> 4;
    const int bj = blockIdx.x * 64, bo = blockIdx.y * 64;
    const int lr = tid >> 4;          // 0..15
    const int lc = (tid & 15) << 2;   // 0..60

    float acc[4][4];
#pragma unroll
    for (int m = 0; m < 4; m++)
#pragma unroll
        for (int n = 0; n < 4; n++) acc[m][n] = 0.f;

    for (int k0 = 0; k0 < K; k0 += 32) {
        float4 a0 = *(const float4*)(W + (size_t)(k0 + lr) * N + bj + lc);
        float4 a1 = *(const float4*)(W + (size_t)(k0 + lr + 16) * N + bj + lc);
        float4 b0 = *(const float4*)(W + (size_t)(k0 + lr) * N + bo + lc);
        float4 b1 = *(const float4*)(W + (size_t)(k0 + lr + 16) * N + bo + lc);
        __syncthreads();
        *(float4*)&As[lr][lc] = a0; *(float4*)&As[lr + 16][lc] = a1;
        *(float4*)&Bs[lr][lc] = b0; *(float4*)&Bs[lr + 16][lc] = b1;
        __syncthreads();
#pragma unroll
        for (int k = 0; k < 32; ++k) {
            float4 av = *(const float4*)&As[k][ty * 4];
            float4 bv = *(const float4*)&Bs[k][tx * 4];
            float am[4] = {av.x, av.y, av.z, av.w};
            float bb[4] = {bv.x, bv.y, bv.z, bv.w};
#pragma unroll
            for (int m = 0; m < 4; m++)
#pragma unroll
                for (int n = 0; n < 4; n++) acc[m][n] += am[m] * bb[n];
        }
    }
#pragma unroll
    for (int m = 0; m < 4; m++) {
        float4 v = make_float4(acc[m][0], acc[m][1], acc[m][2], acc[m][3]);
        *(float4*)(D + (size_t)(bj + ty * 4 + m) * N + bo + tx * 4) = v;
    }
}

// ---------------------------------------------------------------------------
// inv_norm[o] = 1/(d[o][o] + 1e-8)  (norm is exactly the wtw diagonal);
// also zero the spike counter.
// ---------------------------------------------------------------------------
__global__ void colnorm_diag(const float* __restrict__ D, float* __restrict__ invn,
                             unsigned int* __restrict__ counter) {
    int o = blockIdx.x * 256 + threadIdx.x;
    if (o == 0) *counter = 0u;
    invn[o] = 1.0f / (D[(size_t)o * O_ + o] + 1e-8f);
}

// ---------------------------------------------------------------------------
// Sequential scan: one block per batch sample; thread owns 4 CONTIGUOUS
// neurons so each gathered d-row is one dwordx4. Gather batched 4 rows at a
// time; h(t+1) prefetched before the gather.
// ---------------------------------------------------------------------------
__global__ __launch_bounds__(256) void scan_kernel(const float* __restrict__ h,
                                                   const float* __restrict__ d,
                                                   const float* __restrict__ invn,
                                                   const float* __restrict__ bias,
                                                   const float* __restrict__ beta,
                                                   float* __restrict__ out,
                                                   unsigned int* __restrict__ spike_count) {
    __shared__ int lst[2][O_];
    __shared__ int cnt[2];
    __shared__ unsigned int red[256];

    const int tid = threadIdx.x;
    const int b = blockIdx.x;
    const int o4 = tid * 4;
    const float betav = beta[0];
    const float omb = 1.0f - betav;

    const float4 invn4 = *(const float4*)(invn + o4);
    const float4 b4 = *(const float4*)(bias + o4);
    float4 mem4 = make_float4(0.f, 0.f, 0.f, 0.f);

    if (tid < 2) cnt[tid] = 0;
    unsigned int local_count = 0;
    const float* hb = h + (size_t)b * T_ * O_;
    float* ob = out + (size_t)b * T_ * O_;

    float4 hcur = *(const float4*)(hb + o4);   // t = 0
    __syncthreads();

    for (int t = 0; t < T_; ++t) {
        const int p = t & 1, q = p ^ 1;
        const int n = cnt[p];
        __syncthreads();                 // everyone has read n
        if (tid == 0) cnt[p] = 0;        // ready for appends at step t+2

        // prefetch h for t+1 (latency hidden behind the gather)
        float4 hnext = make_float4(0.f, 0.f, 0.f, 0.f);
        if (t + 1 < T_) hnext = *(const float4*)(hb + (size_t)(t + 1) * O_ + o4);

        float4 rst = make_float4(0.f, 0.f, 0.f, 0.f);
        int i = 0;
        for (; i + 4 <= n; i += 4) {
            const int j0 = lst[p][i + 0];
            const int j1 = lst[p][i + 1];
            const int j2 = lst[p][i + 2];
            const int j3 = lst[p][i + 3];
            float4 v0 = *(const float4*)(d + (size_t)j0 * O_ + o4);
            float4 v1 = *(const float4*)(d + (size_t)j1 * O_ + o4);
            float4 v2 = *(const float4*)(d + (size_t)j2 * O_ + o4);
            float4 v3 = *(const float4*)(d + (size_t)j3 * O_ + o4);
            rst.x += (v0.x + v1.x) + (v2.x + v3.x);
            rst.y += (v0.y + v1.y) + (v2.y + v3.y);
            rst.z += (v0.z + v1.z) + (v2.z + v3.z);
            rst.w += (v0.w + v1.w) + (v2.w + v3.w);
        }
        for (; i < n; ++i) {
            const int j = lst[p][i];
            float4 v = *(const float4*)(d + (size_t)j * O_ + o4);
            rst.x += v.x; rst.y += v.y; rst.z += v.z; rst.w += v.w;
        }

        mem4.x = (mem4.x - rst.x) * betav + hcur.x * omb;
        mem4.y = (mem4.y - rst.y) * betav + hcur.y * omb;
        mem4.z = (mem4.z - rst.z) * betav + hcur.z * omb;
        mem4.w = (mem4.w - rst.w) * betav + hcur.w * omb;

        const int s0 = (mem4.x * invn4.x - b4.x) > 0.0f;
        const int s1 = (mem4.y * invn4.y - b4.y) > 0.0f;
        const int s2 = (mem4.z * invn4.z - b4.z) > 0.0f;
        const int s3 = (mem4.w * invn4.w - b4.w) > 0.0f;

        float4 sv = make_float4(s0 ? 1.f : 0.f, s1 ? 1.f : 0.f,
                                s2 ? 1.f : 0.f, s3 ? 1.f : 0.f);
        *(float4*)(ob + (size_t)t * O_ + o4) = sv;
        local_count += (unsigned)(s0 + s1 + s2 + s3);

        if (s0) { int pos = atomicAdd(&cnt[q], 1); lst[q][pos] = o4 + 0; }
        if (s1) { int pos = atomicAdd(&cnt[q], 1); lst[q][pos] = o4 + 1; }
        if (s2) { int pos = atomicAdd(&cnt[q], 1); lst[q][pos] = o4 + 2; }
        if (s3) { int pos = atomicAdd(&cnt[q], 1); lst[q][pos] = o4 + 3; }

        __syncthreads();                 // appends visible for next gather
        hcur = hnext;
    }

    // block reduction of spike count
    red[tid] = local_count;
    __syncthreads();
    for (int s = 128; s > 0; s >>= 1) {
        if (tid < s) red[tid] += red[tid + s];
        __syncthreads();
    }
    if (tid == 0) atomicAdd(spike_count, red[0]);
}

__global__ void finalize_loss(const unsigned int* __restrict__ spike_count,
                              float* __restrict__ loss_out) {
    // count <= 2^24 so float is exact; /2^24 and *0.5 are exact scalings
    *loss_out = 0.5f * ((float)(*spike_count) / 16777216.0f);
}

// ---------------------------------------------------------------------------
extern "C" void kernel_launch(void* const* d_in, const int* in_sizes, int n_in,
                              void* d_out, int out_size, void* d_ws, size_t ws_size,
                              hipStream_t stream) {
    const float* x    = (const float*)d_in[0];   // [B,T,I]
    const float* w    = (const float*)d_in[1];   // [I,O]
    const float* beta = (const float*)d_in[2];   // [1]
    const float* bias = (const float*)d_in[3];   // [O]
    float* out = (float*)d_out;                  // NOUT spikes + 1 loss

    // workspace layout
    char* ws = (char*)d_ws;
    float* h    = (float*)ws;                                   // 64 MiB
    float* dmat = (float*)(ws + (size_t)67108864);              // 4 MiB
    float* invn = (float*)(ws + (size_t)67108864 + 4194304);    // 4 KiB
    unsigned int* cntp = (unsigned int*)(ws + (size_t)67108864 + 4194304 + 4096);

    gemm_xw<<<dim3(M_ / 128, O_ / 128), 256, 0, stream>>>(x, w, h);
    gemm_wtw<<<dim3(O_ / 64, O_ / 64), 256, 0, stream>>>(w, dmat);
    colnorm_diag<<<O_ / 256, 256, 0, stream>>>(dmat, invn, cntp);
    scan_kernel<<<B_, 256, 0, stream>>>(h, dmat, invn, bias, beta, out, cntp);
    finalize_loss<<<1, 1, 0, stream>>>(cntp, out + (size_t)NOUT);
}

// Round 4
// 720.417 us; speedup vs baseline: 1.2492x; 1.2492x over previous
//
#include <hip/hip_runtime.h>

#define B_ 128
#define T_ 128
#define I_ 1024
#define O_ 1024
#define M_ (B_*T_)          // 16384 rows of h
#define NOUT (M_*O_)        // 16777216 spike outputs, loss at index NOUT

// async global->LDS, 16B per lane. LDS dest = wave-uniform base + lane*16.
__device__ __forceinline__ void gld_lds16(const float* g, float* l) {
    __builtin_amdgcn_global_load_lds((const __attribute__((address_space(1))) void*)g,
                                     (__attribute__((address_space(3))) void*)l,
                                     16, 0, 0);
}

// ---------------------------------------------------------------------------
// h = x @ w   (A: [M,K] row-major, B: [K,N] row-major, C: [M,N])
// 128x128 tile, KT=16, 256 threads, 8x8 micro-tile.
// Double-buffered LDS filled by global_load_lds; one barrier per K-tile.
// launch_bounds(256,3): reg budget ~170 -> fits acc 64 + a-cache 32 + b 8
// + addressing WITHOUT the round-3 scratch spill (cap 128 spilled acc ->
// 2.3 GB HBM traffic). kg loop kept rolled so the compiler can't pipeline
// two a-caches and re-blow pressure.
// ---------------------------------------------------------------------------
__global__ __launch_bounds__(256, 3) void gemm_xw(const float* __restrict__ A,
                                                  const float* __restrict__ Bw,
                                                  float* __restrict__ C) {
    const int K = I_, N = O_;
    const int NT = K / 16;
    __shared__ float As2[2][128][16];   // [buf][row][k]  8 KB per buf
    __shared__ float Bs[2][16][128];    // [buf][k][col]  8 KB per buf

    const int tid = threadIdx.x;
    const int tx = tid & 15, ty = tid >> 4;
    const int bm = blockIdx.x * 128, bn = blockIdx.y * 128;

    const float* gA = A + (size_t)(bm + (tid >> 2)) * K + ((tid & 3) << 2);
    const float* gB = Bw + (size_t)(tid >> 5) * N + bn + ((tid & 31) << 2);
    float* lA = (float*)As2 + tid * 4;   // As2[0][tid>>2][(tid&3)*4]
    float* lB = (float*)Bs + tid * 4;    // Bs[0][tid>>5][(tid&31)*4]

    float acc[2][2][4][4];
#pragma unroll
    for (int i = 0; i < 2; i++)
#pragma unroll
        for (int j = 0; j < 2; j++)
#pragma unroll
            for (int m = 0; m < 4; m++)
#pragma unroll
                for (int n = 0; n < 4; n++) acc[i][j][m][n] = 0.f;

    // stage tile 0 into buf 0
    gld_lds16(gA, lA);
    gld_lds16(gA + (size_t)64 * K, lA + 1024);       // rows 64..127
    gld_lds16(gB, lB);
    gld_lds16(gB + (size_t)8 * N, lB + 1024);        // k-rows 8..15
    __syncthreads();

    for (int t = 0; t < NT; ++t) {
        const int cur = t & 1;
        if (t + 1 < NT) {
            const int nxt = cur ^ 1;
            const float* a0 = gA + (t + 1) * 16;
            const float* b0 = gB + (size_t)(t + 1) * 16 * N;
            float* la = lA + nxt * 2048;
            float* lb = lB + nxt * 2048;
            gld_lds16(a0, la);
            gld_lds16(a0 + (size_t)64 * K, la + 1024);
            gld_lds16(b0, lb);
            gld_lds16(b0 + (size_t)8 * N, lb + 1024);
        }
        const float* Ab = (const float*)As2 + cur * 2048;
        const float* Bb = (const float*)Bs + cur * 2048;
#pragma unroll 1
        for (int kg = 0; kg < 4; ++kg) {
            const int kgp = (kg + ty) & 3;               // bank-conflict rotation
            float a[8][4];
#pragma unroll
            for (int r = 0; r < 4; ++r) {
                float4 v0 = *(const float4*)(Ab + (ty * 4 + r) * 16 + kgp * 4);
                float4 v1 = *(const float4*)(Ab + (64 + ty * 4 + r) * 16 + kgp * 4);
                a[r][0] = v0.x; a[r][1] = v0.y; a[r][2] = v0.z; a[r][3] = v0.w;
                a[4 + r][0] = v1.x; a[4 + r][1] = v1.y; a[4 + r][2] = v1.z; a[4 + r][3] = v1.w;
            }
#pragma unroll
            for (int kk = 0; kk < 4; ++kk) {
                const int k = kgp * 4 + kk;
                float4 bv0 = *(const float4*)(Bb + k * 128 + tx * 4);
                float4 bv1 = *(const float4*)(Bb + k * 128 + 64 + tx * 4);
                float bb[8] = {bv0.x, bv0.y, bv0.z, bv0.w,
                               bv1.x, bv1.y, bv1.z, bv1.w};
#pragma unroll
                for (int mi = 0; mi < 2; mi++)
#pragma unroll
                    for (int ni = 0; ni < 2; ni++)
#pragma unroll
                        for (int mm = 0; mm < 4; mm++)
#pragma unroll
                            for (int nn = 0; nn < 4; nn++)
                                acc[mi][ni][mm][nn] += a[mi * 4 + mm][kk] * bb[ni * 4 + nn];
            }
        }
        __syncthreads();
    }

#pragma unroll
    for (int mi = 0; mi < 2; mi++)
#pragma unroll
        for (int mm = 0; mm < 4; mm++) {
            int m = bm + mi * 64 + ty * 4 + mm;
#pragma unroll
            for (int ni = 0; ni < 2; ni++) {
                float4 v = make_float4(acc[mi][ni][mm][0], acc[mi][ni][mm][1],
                                       acc[mi][ni][mm][2], acc[mi][ni][mm][3]);
                *(float4*)(C + (size_t)m * N + bn + ni * 64 + tx * 4) = v;
            }
        }
}

// ---------------------------------------------------------------------------
// d = w^T w   (w: [K=I_, N=O_] row-major). 64x64 tile, KT=32, 256 threads.
// ---------------------------------------------------------------------------
__global__ __launch_bounds__(256) void gemm_wtw(const float* __restrict__ W,
                                                float* __restrict__ D) {
    const int K = I_, N = O_;
    __shared__ float As[32][68];
    __shared__ float Bs[32][68];
    const int tid = threadIdx.x;
    const int tx = tid & 15, ty = tid >> 4;
    const int bj = blockIdx.x * 64, bo = blockIdx.y * 64;
    const int lr = tid >> 4;          // 0..15
    const int lc = (tid & 15) << 2;   // 0..60

    float acc[4][4];
#pragma unroll
    for (int m = 0; m < 4; m++)
#pragma unroll
        for (int n = 0; n < 4; n++) acc[m][n] = 0.f;

    for (int k0 = 0; k0 < K; k0 += 32) {
        float4 a0 = *(const float4*)(W + (size_t)(k0 + lr) * N + bj + lc);
        float4 a1 = *(const float4*)(W + (size_t)(k0 + lr + 16) * N + bj + lc);
        float4 b0 = *(const float4*)(W + (size_t)(k0 + lr) * N + bo + lc);
        float4 b1 = *(const float4*)(W + (size_t)(k0 + lr + 16) * N + bo + lc);
        __syncthreads();
        *(float4*)&As[lr][lc] = a0; *(float4*)&As[lr + 16][lc] = a1;
        *(float4*)&Bs[lr][lc] = b0; *(float4*)&Bs[lr + 16][lc] = b1;
        __syncthreads();
#pragma unroll
        for (int k = 0; k < 32; ++k) {
            float4 av = *(const float4*)&As[k][ty * 4];
            float4 bv = *(const float4*)&Bs[k][tx * 4];
            float am[4] = {av.x, av.y, av.z, av.w};
            float bb[4] = {bv.x, bv.y, bv.z, bv.w};
#pragma unroll
            for (int m = 0; m < 4; m++)
#pragma unroll
                for (int n = 0; n < 4; n++) acc[m][n] += am[m] * bb[n];
        }
    }
#pragma unroll
    for (int m = 0; m < 4; m++) {
        float4 v = make_float4(acc[m][0], acc[m][1], acc[m][2], acc[m][3]);
        *(float4*)(D + (size_t)(bj + ty * 4 + m) * N + bo + tx * 4) = v;
    }
}

// ---------------------------------------------------------------------------
// inv_norm[o] = 1/(d[o][o] + 1e-8); also zero the spike counter.
// ---------------------------------------------------------------------------
__global__ void colnorm_diag(const float* __restrict__ D, float* __restrict__ invn,
                             unsigned int* __restrict__ counter) {
    int o = blockIdx.x * 256 + threadIdx.x;
    if (o == 0) *counter = 0u;
    invn[o] = 1.0f / (D[(size_t)o * O_ + o] + 1e-8f);
}

// ---------------------------------------------------------------------------
// Sequential scan: one block per sample; thread owns 4 contiguous neurons.
// Gather batched 8 rows/wait (halves serialized L2-latency round trips);
// h(t+1) prefetched before the gather.
// ---------------------------------------------------------------------------
__global__ __launch_bounds__(256) void scan_kernel(const float* __restrict__ h,
                                                   const float* __restrict__ d,
                                                   const float* __restrict__ invn,
                                                   const float* __restrict__ bias,
                                                   const float* __restrict__ beta,
                                                   float* __restrict__ out,
                                                   unsigned int* __restrict__ spike_count) {
    __shared__ int lst[2][O_];
    __shared__ int cnt[2];
    __shared__ unsigned int red[256];

    const int tid = threadIdx.x;
    const int b = blockIdx.x;
    const int o4 = tid * 4;
    const float betav = beta[0];
    const float omb = 1.0f - betav;

    const float4 invn4 = *(const float4*)(invn + o4);
    const float4 b4 = *(const float4*)(bias + o4);
    float4 mem4 = make_float4(0.f, 0.f, 0.f, 0.f);

    if (tid < 2) cnt[tid] = 0;
    unsigned int local_count = 0;
    const float* hb = h + (size_t)b * T_ * O_;
    float* ob = out + (size_t)b * T_ * O_;

    float4 hcur = *(const float4*)(hb + o4);   // t = 0
    __syncthreads();

    for (int t = 0; t < T_; ++t) {
        const int p = t & 1, q = p ^ 1;
        const int n = cnt[p];
        __syncthreads();                 // everyone has read n
        if (tid == 0) cnt[p] = 0;        // ready for appends at step t+2

        // prefetch h for t+1 (latency hidden behind the gather)
        float4 hnext = make_float4(0.f, 0.f, 0.f, 0.f);
        if (t + 1 < T_) hnext = *(const float4*)(hb + (size_t)(t + 1) * O_ + o4);

        float4 rst = make_float4(0.f, 0.f, 0.f, 0.f);
        int i = 0;
        for (; i + 8 <= n; i += 8) {
            float4 v[8];
#pragma unroll
            for (int u = 0; u < 8; ++u) {
                const int j = lst[p][i + u];
                v[u] = *(const float4*)(d + (size_t)j * O_ + o4);
            }
#pragma unroll
            for (int u = 0; u < 8; ++u) {
                rst.x += v[u].x; rst.y += v[u].y;
                rst.z += v[u].z; rst.w += v[u].w;
            }
        }
        for (; i < n; ++i) {
            const int j = lst[p][i];
            float4 v = *(const float4*)(d + (size_t)j * O_ + o4);
            rst.x += v.x; rst.y += v.y; rst.z += v.z; rst.w += v.w;
        }

        mem4.x = (mem4.x - rst.x) * betav + hcur.x * omb;
        mem4.y = (mem4.y - rst.y) * betav + hcur.y * omb;
        mem4.z = (mem4.z - rst.z) * betav + hcur.z * omb;
        mem4.w = (mem4.w - rst.w) * betav + hcur.w * omb;

        const int s0 = (mem4.x * invn4.x - b4.x) > 0.0f;
        const int s1 = (mem4.y * invn4.y - b4.y) > 0.0f;
        const int s2 = (mem4.z * invn4.z - b4.z) > 0.0f;
        const int s3 = (mem4.w * invn4.w - b4.w) > 0.0f;

        float4 sv = make_float4(s0 ? 1.f : 0.f, s1 ? 1.f : 0.f,
                                s2 ? 1.f : 0.f, s3 ? 1.f : 0.f);
        *(float4*)(ob + (size_t)t * O_ + o4) = sv;
        local_count += (unsigned)(s0 + s1 + s2 + s3);

        if (s0) { int pos = atomicAdd(&cnt[q], 1); lst[q][pos] = o4 + 0; }
        if (s1) { int pos = atomicAdd(&cnt[q], 1); lst[q][pos] = o4 + 1; }
        if (s2) { int pos = atomicAdd(&cnt[q], 1); lst[q][pos] = o4 + 2; }
        if (s3) { int pos = atomicAdd(&cnt[q], 1); lst[q][pos] = o4 + 3; }

        __syncthreads();                 // appends visible for next gather
        hcur = hnext;
    }

    // block reduction of spike count
    red[tid] = local_count;
    __syncthreads();
    for (int s = 128; s > 0; s >>= 1) {
        if (tid < s) red[tid] += red[tid + s];
        __syncthreads();
    }
    if (tid == 0) atomicAdd(spike_count, red[0]);
}

__global__ void finalize_loss(const unsigned int* __restrict__ spike_count,
                              float* __restrict__ loss_out) {
    // count <= 2^24 so float is exact; /2^24 and *0.5 are exact scalings
    *loss_out = 0.5f * ((float)(*spike_count) / 16777216.0f);
}

// ---------------------------------------------------------------------------
extern "C" void kernel_launch(void* const* d_in, const int* in_sizes, int n_in,
                              void* d_out, int out_size, void* d_ws, size_t ws_size,
                              hipStream_t stream) {
    const float* x    = (const float*)d_in[0];   // [B,T,I]
    const float* w    = (const float*)d_in[1];   // [I,O]
    const float* beta = (const float*)d_in[2];   // [1]
    const float* bias = (const float*)d_in[3];   // [O]
    float* out = (float*)d_out;                  // NOUT spikes + 1 loss

    // workspace layout
    char* ws = (char*)d_ws;
    float* h    = (float*)ws;                                   // 64 MiB
    float* dmat = (float*)(ws + (size_t)67108864);              // 4 MiB
    float* invn = (float*)(ws + (size_t)67108864 + 4194304);    // 4 KiB
    unsigned int* cntp = (unsigned int*)(ws + (size_t)67108864 + 4194304 + 4096);

    gemm_xw<<<dim3(M_ / 128, O_ / 128), 256, 0, stream>>>(x, w, h);
    gemm_wtw<<<dim3(O_ / 64, O_ / 64), 256, 0, stream>>>(w, dmat);
    colnorm_diag<<<O_ / 256, 256, 0, stream>>>(dmat, invn, cntp);
    scan_kernel<<<B_, 256, 0, stream>>>(h, dmat, invn, bias, beta, out, cntp);
    finalize_loss<<<1, 1, 0, stream>>>(cntp, out + (size_t)NOUT);
}

// Round 5
// 555.697 us; speedup vs baseline: 1.6195x; 1.2964x over previous
//
#include <hip/hip_runtime.h>

#define B_ 128
#define T_ 128
#define I_ 1024
#define O_ 1024
#define M_ (B_*T_)          // 16384 rows of h
#define NOUT (M_*O_)        // 16777216 spike outputs, loss at index NOUT

typedef __attribute__((ext_vector_type(8))) short short8;   // 8 bf16 = 4 VGPR
typedef __attribute__((ext_vector_type(4))) float floatx4;  // MFMA acc

// async global->LDS, 16B per lane. LDS dest = wave-uniform base + lane*16.
__device__ __forceinline__ void gld_lds16(const void* g, void* l) {
    __builtin_amdgcn_global_load_lds((const __attribute__((address_space(1))) void*)g,
                                     (__attribute__((address_space(3))) void*)l,
                                     16, 0, 0);
}

// Dekker-style exact 3-way bf16 split by truncation: x = hi + mid + lo + r,
// |r| <~ 2^-21 |x|. All subtractions exact (truncation of own value).
__device__ __forceinline__ void split3(float x, unsigned short& h,
                                       unsigned short& m, unsigned short& l) {
    unsigned int b0 = __float_as_uint(x);
    h = (unsigned short)(b0 >> 16);
    float r1 = x - __uint_as_float(b0 & 0xFFFF0000u);
    unsigned int b1 = __float_as_uint(r1);
    m = (unsigned short)(b1 >> 16);
    float r2 = r1 - __uint_as_float(b1 & 0xFFFF0000u);
    l = (unsigned short)(__float_as_uint(r2) >> 16);
}

// ---------------------------------------------------------------------------
// split_wt: w [K=1024][N=1024] f32 -> three TRANSPOSED bf16 planes
// wt_p[N][K] (p = hi/mid/lo), via 64x64 LDS tile transpose.
// ---------------------------------------------------------------------------
__global__ __launch_bounds__(256) void split_wt(const float* __restrict__ W,
                                                unsigned short* __restrict__ WTh,
                                                unsigned short* __restrict__ WTm,
                                                unsigned short* __restrict__ WTl) {
    __shared__ float t[64][65];
    const int tid = threadIdx.x;
    const int tx = tid & 63, ty4 = tid >> 6;      // 0..63, 0..3
    const int r0 = blockIdx.x * 64, c0 = blockIdx.y * 64;
#pragma unroll
    for (int j = 0; j < 16; ++j) {
        int row = j * 4 + ty4;
        t[row][tx] = W[(size_t)(r0 + row) * O_ + c0 + tx];
    }
    __syncthreads();
#pragma unroll
    for (int j = 0; j < 16; ++j) {
        int i = j * 4 + ty4;                      // output row = col c0+i
        float v = t[tx][i];
        unsigned short h, m, l;
        split3(v, h, m, l);
        size_t off = (size_t)(c0 + i) * I_ + r0 + tx;
        WTh[off] = h; WTm[off] = m; WTl[off] = l;
    }
}

// ---------------------------------------------------------------------------
// h = x @ w via split-bf16 MFMA. 128x128 block tile, BK=32, 256 threads,
// 4 waves each computing 64x64 as 4x4 tiles of mfma_f32_16x16x32_bf16.
// A (x) staged fp32 by global_load_lds and split in-register (3 planes);
// B (w) staged from pre-split TRANSPOSED bf16 planes (k-contiguous frags).
// 8 of 9 products kept (drop lo*lo): error ~1e-7 absolute in h.
// Fragment maps (verified m89/m91/m120): A[m=lane&15][k=quad*8+j],
// B[k=quad*8+j][n=lane&15], C/D row=quad*4+reg, col=lane&15.
// ---------------------------------------------------------------------------
__global__ __launch_bounds__(256, 3) void gemm_h_split(const float* __restrict__ X,
                                                       const unsigned short* __restrict__ WTh,
                                                       const unsigned short* __restrict__ WTm,
                                                       const unsigned short* __restrict__ WTl,
                                                       float* __restrict__ H) {
    const int K = I_, N = O_;
    __shared__ float Af[128 * 32];             // [row][k] fp32, 16 KB
    __shared__ unsigned short Bs[3][128 * 32]; // [plane][col][k] bf16, 8 KB each

    const int tid = threadIdx.x;
    const int lane = tid & 63;
    const int wid = tid >> 6;                  // 0..3
    const int wrow = wid >> 1, wcol = wid & 1;
    const int l15 = lane & 15, quad = lane >> 4;
    const int bm = blockIdx.x * 128, bn = blockIdx.y * 128;

    floatx4 acc[4][4];
#pragma unroll
    for (int mt = 0; mt < 4; ++mt)
#pragma unroll
        for (int nt = 0; nt < 4; ++nt) acc[mt][nt] = (floatx4)(0.f);

    for (int kt = 0; kt < 32; ++kt) {
        const int k0 = kt * 32;
        __syncthreads();                       // previous compute done with LDS
        // --- stage A (fp32): 4 slots/thread; slot s: row=slot>>3, chunk=slot&7
#pragma unroll
        for (int s = 0; s < 4; ++s) {
            int slot = tid + 256 * s;
            int row = slot >> 3, ch = slot & 7;
            gld_lds16(X + (size_t)(bm + row) * K + k0 + ch * 4, (float*)Af + (size_t)slot * 4);
        }
        // --- stage B planes (bf16): 2 slots/thread/plane; slot: col=slot>>2, chunk=slot&3
#pragma unroll
        for (int s = 0; s < 2; ++s) {
            int slot = tid + 256 * s;
            int col = slot >> 2, ch = slot & 3;
            size_t goff = (size_t)(bn + col) * K + k0 + ch * 8;
            gld_lds16(WTh + goff, (unsigned short*)Bs + (size_t)slot * 8);
            gld_lds16(WTm + goff, (unsigned short*)Bs + 4096 + (size_t)slot * 8);
            gld_lds16(WTl + goff, (unsigned short*)Bs + 8192 + (size_t)slot * 8);
        }
        __syncthreads();                       // vmcnt drain -> LDS visible

        // --- load + split A fragments (3 planes x 4 m-tiles)
        short8 Ah[4], Am[4], Al[4];
#pragma unroll
        for (int mt = 0; mt < 4; ++mt) {
            int row = wrow * 64 + mt * 16 + l15;
            const float* ap = (const float*)Af + row * 32 + quad * 8;
            float4 x0 = *(const float4*)(ap);
            float4 x1 = *(const float4*)(ap + 4);
            float xs[8] = {x0.x, x0.y, x0.z, x0.w, x1.x, x1.y, x1.z, x1.w};
#pragma unroll
            for (int j = 0; j < 8; ++j) {
                unsigned short hh, mm, ll;
                split3(xs[j], hh, mm, ll);
                Ah[mt][j] = (short)hh; Am[mt][j] = (short)mm; Al[mt][j] = (short)ll;
            }
        }
        // --- products: (pa,pb) for pa in {h,m,l(pb<2)}, pb in {h,m,l}
#pragma unroll
        for (int pb = 0; pb < 3; ++pb) {
            short8 Bf[4];
#pragma unroll
            for (int nt = 0; nt < 4; ++nt) {
                int col = wcol * 64 + nt * 16 + l15;
                Bf[nt] = *((const short8*)((const unsigned short*)Bs + pb * 4096 + col * 32 + quad * 8));
            }
#pragma unroll
            for (int nt = 0; nt < 4; ++nt)
#pragma unroll
                for (int mt = 0; mt < 4; ++mt) {
                    acc[mt][nt] = __builtin_amdgcn_mfma_f32_16x16x32_bf16(Ah[mt], Bf[nt], acc[mt][nt], 0, 0, 0);
                    acc[mt][nt] = __builtin_amdgcn_mfma_f32_16x16x32_bf16(Am[mt], Bf[nt], acc[mt][nt], 0, 0, 0);
                    if (pb < 2)
                        acc[mt][nt] = __builtin_amdgcn_mfma_f32_16x16x32_bf16(Al[mt], Bf[nt], acc[mt][nt], 0, 0, 0);
                }
        }
    }

    // --- epilogue: C/D row = quad*4 + reg, col = lane&15
#pragma unroll
    for (int mt = 0; mt < 4; ++mt)
#pragma unroll
        for (int nt = 0; nt < 4; ++nt) {
            int grow = bm + wrow * 64 + mt * 16 + quad * 4;
            int gcol = bn + wcol * 64 + nt * 16 + l15;
            float* hp = H + (size_t)grow * N + gcol;
#pragma unroll
            for (int r = 0; r < 4; ++r) hp[(size_t)r * N] = acc[mt][nt][r];
        }
}

// ---------------------------------------------------------------------------
// d = w^T w   (fp32 exact-class; matches reference rounding that passed).
// ---------------------------------------------------------------------------
__global__ __launch_bounds__(256) void gemm_wtw(const float* __restrict__ W,
                                                float* __restrict__ D) {
    const int K = I_, N = O_;
    __shared__ float As[32][68];
    __shared__ float Bs[32][68];
    const int tid = threadIdx.x;
    const int tx = tid & 15, ty = tid >> 4;
    const int bj = blockIdx.x * 64, bo = blockIdx.y * 64;
    const int lr = tid >> 4;
    const int lc = (tid & 15) << 2;

    float acc[4][4];
#pragma unroll
    for (int m = 0; m < 4; m++)
#pragma unroll
        for (int n = 0; n < 4; n++) acc[m][n] = 0.f;

    for (int k0 = 0; k0 < K; k0 += 32) {
        float4 a0 = *(const float4*)(W + (size_t)(k0 + lr) * N + bj + lc);
        float4 a1 = *(const float4*)(W + (size_t)(k0 + lr + 16) * N + bj + lc);
        float4 b0 = *(const float4*)(W + (size_t)(k0 + lr) * N + bo + lc);
        float4 b1 = *(const float4*)(W + (size_t)(k0 + lr + 16) * N + bo + lc);
        __syncthreads();
        *(float4*)&As[lr][lc] = a0; *(float4*)&As[lr + 16][lc] = a1;
        *(float4*)&Bs[lr][lc] = b0; *(float4*)&Bs[lr + 16][lc] = b1;
        __syncthreads();
#pragma unroll
        for (int k = 0; k < 32; ++k) {
            float4 av = *(const float4*)&As[k][ty * 4];
            float4 bv = *(const float4*)&Bs[k][tx * 4];
            float am[4] = {av.x, av.y, av.z, av.w};
            float bb[4] = {bv.x, bv.y, bv.z, bv.w};
#pragma unroll
            for (int m = 0; m < 4; m++)
#pragma unroll
                for (int n = 0; n < 4; n++) acc[m][n] += am[m] * bb[n];
        }
    }
#pragma unroll
    for (int m = 0; m < 4; m++) {
        float4 v = make_float4(acc[m][0], acc[m][1], acc[m][2], acc[m][3]);
        *(float4*)(D + (size_t)(bj + ty * 4 + m) * N + bo + tx * 4) = v;
    }
}

// inv_norm[o] = 1/(d[o][o] + 1e-8); also zero the spike counter.
__global__ void colnorm_diag(const float* __restrict__ D, float* __restrict__ invn,
                             unsigned int* __restrict__ counter) {
    int o = blockIdx.x * 256 + threadIdx.x;
    if (o == 0) *counter = 0u;
    invn[o] = 1.0f / (D[(size_t)o * O_ + o] + 1e-8f);
}

// ---------------------------------------------------------------------------
// Sequential scan: one block per sample; thread owns 4 contiguous neurons.
// Gather batched 16 rows/wait; ballot-aggregated spike-list appends
// (one LDS atomic per wave per slot instead of per-lane atomics).
// ---------------------------------------------------------------------------
__global__ __launch_bounds__(256) void scan_kernel(const float* __restrict__ h,
                                                   const float* __restrict__ d,
                                                   const float* __restrict__ invn,
                                                   const float* __restrict__ bias,
                                                   const float* __restrict__ beta,
                                                   float* __restrict__ out,
                                                   unsigned int* __restrict__ spike_count) {
    __shared__ int lst[2][O_];
    __shared__ int cnt[2];
    __shared__ unsigned int red[256];

    const int tid = threadIdx.x;
    const int lane = tid & 63;
    const int b = blockIdx.x;
    const int o4 = tid * 4;
    const float betav = beta[0];
    const float omb = 1.0f - betav;

    const float4 invn4 = *(const float4*)(invn + o4);
    const float4 b4 = *(const float4*)(bias + o4);
    float4 mem4 = make_float4(0.f, 0.f, 0.f, 0.f);

    if (tid < 2) cnt[tid] = 0;
    unsigned int local_count = 0;
    const float* hb = h + (size_t)b * T_ * O_;
    float* ob = out + (size_t)b * T_ * O_;
    const unsigned long long below = (lane == 63) ? 0xFFFFFFFFFFFFFFFFull >> 1
                                                  : ((1ull << lane) - 1ull);

    float4 hcur = *(const float4*)(hb + o4);   // t = 0
    __syncthreads();

    for (int t = 0; t < T_; ++t) {
        const int p = t & 1, q = p ^ 1;
        const int n = cnt[p];
        __syncthreads();
        if (tid == 0) cnt[p] = 0;

        float4 hnext = make_float4(0.f, 0.f, 0.f, 0.f);
        if (t + 1 < T_) hnext = *(const float4*)(hb + (size_t)(t + 1) * O_ + o4);

        float4 rst = make_float4(0.f, 0.f, 0.f, 0.f);
        int i = 0;
        for (; i + 16 <= n; i += 16) {
            float4 v[16];
#pragma unroll
            for (int u = 0; u < 16; ++u) {
                const int j = lst[p][i + u];
                v[u] = *(const float4*)(d + (size_t)j * O_ + o4);
            }
#pragma unroll
            for (int u = 0; u < 16; ++u) {
                rst.x += v[u].x; rst.y += v[u].y;
                rst.z += v[u].z; rst.w += v[u].w;
            }
        }
        for (; i + 4 <= n; i += 4) {
            float4 v[4];
#pragma unroll
            for (int u = 0; u < 4; ++u) {
                const int j = lst[p][i + u];
                v[u] = *(const float4*)(d + (size_t)j * O_ + o4);
            }
#pragma unroll
            for (int u = 0; u < 4; ++u) {
                rst.x += v[u].x; rst.y += v[u].y;
                rst.z += v[u].z; rst.w += v[u].w;
            }
        }
        for (; i < n; ++i) {
            const int j = lst[p][i];
            float4 v = *(const float4*)(d + (size_t)j * O_ + o4);
            rst.x += v.x; rst.y += v.y; rst.z += v.z; rst.w += v.w;
        }

        mem4.x = (mem4.x - rst.x) * betav + hcur.x * omb;
        mem4.y = (mem4.y - rst.y) * betav + hcur.y * omb;
        mem4.z = (mem4.z - rst.z) * betav + hcur.z * omb;
        mem4.w = (mem4.w - rst.w) * betav + hcur.w * omb;

        const int s[4] = {(mem4.x * invn4.x - b4.x) > 0.0f,
                          (mem4.y * invn4.y - b4.y) > 0.0f,
                          (mem4.z * invn4.z - b4.z) > 0.0f,
                          (mem4.w * invn4.w - b4.w) > 0.0f};

        float4 sv = make_float4(s[0] ? 1.f : 0.f, s[1] ? 1.f : 0.f,
                                s[2] ? 1.f : 0.f, s[3] ? 1.f : 0.f);
        *(float4*)(ob + (size_t)t * O_ + o4) = sv;
        local_count += (unsigned)(s[0] + s[1] + s[2] + s[3]);

        // ballot-aggregated appends: one LDS atomic per wave per slot
#pragma unroll
        for (int u = 0; u < 4; ++u) {
            unsigned long long mask = __ballot(s[u]);
            int base = 0;
            if (lane == 0 && mask) base = atomicAdd(&cnt[q], __popcll(mask));
            base = __shfl(base, 0, 64);
            if (s[u]) lst[q][base + __popcll(mask & below)] = o4 + u;
        }

        __syncthreads();
        hcur = hnext;
    }

    red[tid] = local_count;
    __syncthreads();
    for (int st = 128; st > 0; st >>= 1) {
        if (tid < st) red[tid] += red[tid + st];
        __syncthreads();
    }
    if (tid == 0) atomicAdd(spike_count, red[0]);
}

__global__ void finalize_loss(const unsigned int* __restrict__ spike_count,
                              float* __restrict__ loss_out) {
    *loss_out = 0.5f * ((float)(*spike_count) / 16777216.0f);
}

// ---------------------------------------------------------------------------
extern "C" void kernel_launch(void* const* d_in, const int* in_sizes, int n_in,
                              void* d_out, int out_size, void* d_ws, size_t ws_size,
                              hipStream_t stream) {
    const float* x    = (const float*)d_in[0];   // [B,T,I]
    const float* w    = (const float*)d_in[1];   // [I,O]
    const float* beta = (const float*)d_in[2];   // [1]
    const float* bias = (const float*)d_in[3];   // [O]
    float* out = (float*)d_out;                  // NOUT spikes + 1 loss

    // workspace layout (~74 MB total)
    char* ws = (char*)d_ws;
    float* h    = (float*)ws;                                     // 64 MiB
    float* dmat = (float*)(ws + (size_t)67108864);                // 4 MiB
    float* invn = (float*)(ws + (size_t)71303168);                // 4 KiB
    unsigned int* cntp = (unsigned int*)(ws + (size_t)71307264);  // 4 KiB
    unsigned short* wt_h = (unsigned short*)(ws + (size_t)71311360);  // 2 MiB
    unsigned short* wt_m = (unsigned short*)(ws + (size_t)73408512);  // 2 MiB
    unsigned short* wt_l = (unsigned short*)(ws + (size_t)75505664);  // 2 MiB

    split_wt<<<dim3(I_ / 64, O_ / 64), 256, 0, stream>>>(w, wt_h, wt_m, wt_l);
    gemm_h_split<<<dim3(M_ / 128, O_ / 128), 256, 0, stream>>>(x, wt_h, wt_m, wt_l, h);
    gemm_wtw<<<dim3(O_ / 64, O_ / 64), 256, 0, stream>>>(w, dmat);
    colnorm_diag<<<O_ / 256, 256, 0, stream>>>(dmat, invn, cntp);
    scan_kernel<<<B_, 256, 0, stream>>>(h, dmat, invn, bias, beta, out, cntp);
    finalize_loss<<<1, 1, 0, stream>>>(cntp, out + (size_t)NOUT);
}

// Round 6
// 538.057 us; speedup vs baseline: 1.6726x; 1.0328x over previous
//
#include <hip/hip_runtime.h>

#define B_ 128
#define T_ 128
#define I_ 1024
#define O_ 1024
#define M_ (B_*T_)          // 16384 rows of h
#define NOUT (M_*O_)        // 16777216 spike outputs, loss at index NOUT

typedef __attribute__((ext_vector_type(8))) short short8;   // 8 bf16 = 4 VGPR
typedef __attribute__((ext_vector_type(4))) float floatx4;  // MFMA acc

// async global->LDS, 16B per lane. LDS dest = wave-uniform base + lane*16.
__device__ __forceinline__ void gld_lds16(const void* g, void* l) {
    __builtin_amdgcn_global_load_lds((const __attribute__((address_space(1))) void*)g,
                                     (__attribute__((address_space(3))) void*)l,
                                     16, 0, 0);
}

// Dekker-style exact 3-way bf16 split by truncation: x = hi + mid + lo + r,
// |r| <~ 2^-21 |x|. All subtractions exact (truncation of own value).
__device__ __forceinline__ void split3(float x, unsigned short& h,
                                       unsigned short& m, unsigned short& l) {
    unsigned int b0 = __float_as_uint(x);
    h = (unsigned short)(b0 >> 16);
    float r1 = x - __uint_as_float(b0 & 0xFFFF0000u);
    unsigned int b1 = __float_as_uint(r1);
    m = (unsigned short)(b1 >> 16);
    float r2 = r1 - __uint_as_float(b1 & 0xFFFF0000u);
    l = (unsigned short)(__float_as_uint(r2) >> 16);
}

// ---------------------------------------------------------------------------
// split_x: x [M,K] f32 -> 3 bf16 planes, same layout. Pure memory pass.
// ---------------------------------------------------------------------------
__global__ __launch_bounds__(256) void split_x(const float* __restrict__ X,
                                               unsigned short* __restrict__ Xh,
                                               unsigned short* __restrict__ Xm,
                                               unsigned short* __restrict__ Xl) {
    size_t base = ((size_t)blockIdx.x * 256 + threadIdx.x) * 4;
    float4 v = *(const float4*)(X + base);
    ushort4 hh, mm, ll;
    split3(v.x, hh.x, mm.x, ll.x);
    split3(v.y, hh.y, mm.y, ll.y);
    split3(v.z, hh.z, mm.z, ll.z);
    split3(v.w, hh.w, mm.w, ll.w);
    *(ushort4*)(Xh + base) = hh;
    *(ushort4*)(Xm + base) = mm;
    *(ushort4*)(Xl + base) = ll;
}

// ---------------------------------------------------------------------------
// split_wt: w [K][N] f32 -> three TRANSPOSED bf16 planes wt_p[N][K].
// ---------------------------------------------------------------------------
__global__ __launch_bounds__(256) void split_wt(const float* __restrict__ W,
                                                unsigned short* __restrict__ WTh,
                                                unsigned short* __restrict__ WTm,
                                                unsigned short* __restrict__ WTl) {
    __shared__ float t[64][65];
    const int tid = threadIdx.x;
    const int tx = tid & 63, ty4 = tid >> 6;
    const int r0 = blockIdx.x * 64, c0 = blockIdx.y * 64;
#pragma unroll
    for (int j = 0; j < 16; ++j) {
        int row = j * 4 + ty4;
        t[row][tx] = W[(size_t)(r0 + row) * O_ + c0 + tx];
    }
    __syncthreads();
#pragma unroll
    for (int j = 0; j < 16; ++j) {
        int i = j * 4 + ty4;
        float v = t[tx][i];
        unsigned short h, m, l;
        split3(v, h, m, l);
        size_t off = (size_t)(c0 + i) * I_ + r0 + tx;
        WTh[off] = h; WTm[off] = m; WTl[off] = l;
    }
}

// ---------------------------------------------------------------------------
// h = x @ w, all-bf16 split MFMA. 128x128 tile, BK=32, 256 threads,
// 4 waves x (64x64), mfma_f32_16x16x32_bf16, 8 of 9 plane products.
// 6 planes staged in LDS (48 KB) by global_load_lds with XOR chunk swizzle:
//   LDS chunk c of row r holds global chunk c ^ ((r>>1)&3)  (chunk = 16 B).
// Reader inverts. This spreads the 16 frag-read lanes over 8 bank-groups
// (2-way only, free per m136) vs 8/16-way conflicts of the plain layout
// (r5: 1.9e7 conflict cycles).
// Fragment maps (verified m89/m91): A[m=lane&15][k=quad*8+j] from Xp[row][k],
// B[k][n=lane&15] from WTp[col][k]; C/D row=quad*4+reg, col=lane&15.
// ---------------------------------------------------------------------------
__global__ __launch_bounds__(256, 3) void gemm_h_mfma(
        const unsigned short* __restrict__ Xh, const unsigned short* __restrict__ Xm,
        const unsigned short* __restrict__ Xl, const unsigned short* __restrict__ WTh,
        const unsigned short* __restrict__ WTm, const unsigned short* __restrict__ WTl,
        float* __restrict__ H) {
    const int K = I_, N = O_;
    __shared__ unsigned short P[6][128 * 32];   // 6 planes x 8 KB = 48 KB

    const int tid = threadIdx.x;
    const int lane = tid & 63;
    const int wid = tid >> 6;
    const int wrow = wid >> 1, wcol = wid & 1;
    const int l15 = lane & 15, quad = lane >> 4;
    const int bm = blockIdx.x * 128, bn = blockIdx.y * 128;

    // staging: slot = tid + 256*s; row = slot>>2 (4x16B chunks per 32-short row),
    // ch = slot&3; source chunk = ch ^ ((row>>1)&3). s=1 adds 64 rows (swizzle
    // index (row>>1)&3 unchanged: +64 rows -> +32 in row>>1).
    const int srow = tid >> 2, sch = tid & 3;
    const int schg = sch ^ ((srow >> 1) & 3);
    const unsigned short* gsrc[6];
    gsrc[0] = Xh  + (size_t)(bm + srow) * K + schg * 8;
    gsrc[1] = Xm  + (size_t)(bm + srow) * K + schg * 8;
    gsrc[2] = Xl  + (size_t)(bm + srow) * K + schg * 8;
    gsrc[3] = WTh + (size_t)(bn + srow) * K + schg * 8;
    gsrc[4] = WTm + (size_t)(bn + srow) * K + schg * 8;
    gsrc[5] = WTl + (size_t)(bn + srow) * K + schg * 8;

    floatx4 acc[4][4];
#pragma unroll
    for (int mt = 0; mt < 4; ++mt)
#pragma unroll
        for (int nt = 0; nt < 4; ++nt) acc[mt][nt] = (floatx4)(0.f);

    for (int kt = 0; kt < 32; ++kt) {
        const int k0 = kt * 32;
        __syncthreads();                       // all reads of P done
#pragma unroll
        for (int p = 0; p < 6; ++p) {
            unsigned short* dst = (unsigned short*)P + p * 4096 + tid * 8;
            gld_lds16(gsrc[p] + k0, dst);
            gld_lds16(gsrc[p] + (size_t)64 * K + k0, dst + 2048);
        }
        __syncthreads();                       // vmcnt drain -> LDS visible

        short8 Af[3][4];
#pragma unroll
        for (int pa = 0; pa < 3; ++pa)
#pragma unroll
            for (int mt = 0; mt < 4; ++mt) {
                int row = wrow * 64 + mt * 16 + l15;
                int chk = quad ^ ((row >> 1) & 3);
                Af[pa][mt] = *(const short8*)((const unsigned short*)P + pa * 4096 + row * 32 + chk * 8);
            }
#pragma unroll
        for (int pb = 0; pb < 3; ++pb) {
            short8 Bf[4];
#pragma unroll
            for (int nt = 0; nt < 4; ++nt) {
                int col = wcol * 64 + nt * 16 + l15;
                int chk = quad ^ ((col >> 1) & 3);
                Bf[nt] = *(const short8*)((const unsigned short*)P + (3 + pb) * 4096 + col * 32 + chk * 8);
            }
#pragma unroll
            for (int nt = 0; nt < 4; ++nt)
#pragma unroll
                for (int mt = 0; mt < 4; ++mt) {
                    acc[mt][nt] = __builtin_amdgcn_mfma_f32_16x16x32_bf16(Af[0][mt], Bf[nt], acc[mt][nt], 0, 0, 0);
                    acc[mt][nt] = __builtin_amdgcn_mfma_f32_16x16x32_bf16(Af[1][mt], Bf[nt], acc[mt][nt], 0, 0, 0);
                    if (pb < 2)
                        acc[mt][nt] = __builtin_amdgcn_mfma_f32_16x16x32_bf16(Af[2][mt], Bf[nt], acc[mt][nt], 0, 0, 0);
                }
        }
    }

    // epilogue: C/D row = quad*4 + reg, col = lane&15
#pragma unroll
    for (int mt = 0; mt < 4; ++mt)
#pragma unroll
        for (int nt = 0; nt < 4; ++nt) {
            int grow = bm + wrow * 64 + mt * 16 + quad * 4;
            int gcol = bn + wcol * 64 + nt * 16 + l15;
            float* hp = H + (size_t)grow * N + gcol;
#pragma unroll
            for (int r = 0; r < 4; ++r) hp[(size_t)r * N] = acc[mt][nt][r];
        }
}

// ---------------------------------------------------------------------------
// d = w^T w   (fp32 exact-class).
// ---------------------------------------------------------------------------
__global__ __launch_bounds__(256) void gemm_wtw(const float* __restrict__ W,
                                                float* __restrict__ D) {
    const int K = I_, N = O_;
    __shared__ float As[32][68];
    __shared__ float Bs[32][68];
    const int tid = threadIdx.x;
    const int tx = tid & 15, ty = tid >> 4;
    const int bj = blockIdx.x * 64, bo = blockIdx.y * 64;
    const int lr = tid >> 4;
    const int lc = (tid & 15) << 2;

    float acc[4][4];
#pragma unroll
    for (int m = 0; m < 4; m++)
#pragma unroll
        for (int n = 0; n < 4; n++) acc[m][n] = 0.f;

    for (int k0 = 0; k0 < K; k0 += 32) {
        float4 a0 = *(const float4*)(W + (size_t)(k0 + lr) * N + bj + lc);
        float4 a1 = *(const float4*)(W + (size_t)(k0 + lr + 16) * N + bj + lc);
        float4 b0 = *(const float4*)(W + (size_t)(k0 + lr) * N + bo + lc);
        float4 b1 = *(const float4*)(W + (size_t)(k0 + lr + 16) * N + bo + lc);
        __syncthreads();
        *(float4*)&As[lr][lc] = a0; *(float4*)&As[lr + 16][lc] = a1;
        *(float4*)&Bs[lr][lc] = b0; *(float4*)&Bs[lr + 16][lc] = b1;
        __syncthreads();
#pragma unroll
        for (int k = 0; k < 32; ++k) {
            float4 av = *(const float4*)&As[k][ty * 4];
            float4 bv = *(const float4*)&Bs[k][tx * 4];
            float am[4] = {av.x, av.y, av.z, av.w};
            float bb[4] = {bv.x, bv.y, bv.z, bv.w};
#pragma unroll
            for (int m = 0; m < 4; m++)
#pragma unroll
                for (int n = 0; n < 4; n++) acc[m][n] += am[m] * bb[n];
        }
    }
#pragma unroll
    for (int m = 0; m < 4; m++) {
        float4 v = make_float4(acc[m][0], acc[m][1], acc[m][2], acc[m][3]);
        *(float4*)(D + (size_t)(bj + ty * 4 + m) * N + bo + tx * 4) = v;
    }
}

// inv_norm[o] = 1/(d[o][o] + 1e-8); also zero the spike counter.
__global__ void colnorm_diag(const float* __restrict__ D, float* __restrict__ invn,
                             unsigned int* __restrict__ counter) {
    int o = blockIdx.x * 256 + threadIdx.x;
    if (o == 0) *counter = 0u;
    invn[o] = 1.0f / (D[(size_t)o * O_ + o] + 1e-8f);
}

// ---------------------------------------------------------------------------
// Sequential scan: one block per sample; thread owns 4 contiguous neurons.
// Gather batched 16 rows/wait; ballot-aggregated spike-list appends.
// ---------------------------------------------------------------------------
__global__ __launch_bounds__(256) void scan_kernel(const float* __restrict__ h,
                                                   const float* __restrict__ d,
                                                   const float* __restrict__ invn,
                                                   const float* __restrict__ bias,
                                                   const float* __restrict__ beta,
                                                   float* __restrict__ out,
                                                   unsigned int* __restrict__ spike_count) {
    __shared__ int lst[2][O_];
    __shared__ int cnt[2];
    __shared__ unsigned int red[256];

    const int tid = threadIdx.x;
    const int lane = tid & 63;
    const int b = blockIdx.x;
    const int o4 = tid * 4;
    const float betav = beta[0];
    const float omb = 1.0f - betav;

    const float4 invn4 = *(const float4*)(invn + o4);
    const float4 b4 = *(const float4*)(bias + o4);
    float4 mem4 = make_float4(0.f, 0.f, 0.f, 0.f);

    if (tid < 2) cnt[tid] = 0;
    unsigned int local_count = 0;
    const float* hb = h + (size_t)b * T_ * O_;
    float* ob = out + (size_t)b * T_ * O_;
    const unsigned long long below = (lane == 63) ? 0xFFFFFFFFFFFFFFFFull >> 1
                                                  : ((1ull << lane) - 1ull);

    float4 hcur = *(const float4*)(hb + o4);   // t = 0
    __syncthreads();

    for (int t = 0; t < T_; ++t) {
        const int p = t & 1, q = p ^ 1;
        const int n = cnt[p];
        __syncthreads();
        if (tid == 0) cnt[p] = 0;

        float4 hnext = make_float4(0.f, 0.f, 0.f, 0.f);
        if (t + 1 < T_) hnext = *(const float4*)(hb + (size_t)(t + 1) * O_ + o4);

        float4 rst = make_float4(0.f, 0.f, 0.f, 0.f);
        int i = 0;
        for (; i + 16 <= n; i += 16) {
            float4 v[16];
#pragma unroll
            for (int u = 0; u < 16; ++u) {
                const int j = lst[p][i + u];
                v[u] = *(const float4*)(d + (size_t)j * O_ + o4);
            }
#pragma unroll
            for (int u = 0; u < 16; ++u) {
                rst.x += v[u].x; rst.y += v[u].y;
                rst.z += v[u].z; rst.w += v[u].w;
            }
        }
        for (; i + 4 <= n; i += 4) {
            float4 v[4];
#pragma unroll
            for (int u = 0; u < 4; ++u) {
                const int j = lst[p][i + u];
                v[u] = *(const float4*)(d + (size_t)j * O_ + o4);
            }
#pragma unroll
            for (int u = 0; u < 4; ++u) {
                rst.x += v[u].x; rst.y += v[u].y;
                rst.z += v[u].z; rst.w += v[u].w;
            }
        }
        for (; i < n; ++i) {
            const int j = lst[p][i];
            float4 v = *(const float4*)(d + (size_t)j * O_ + o4);
            rst.x += v.x; rst.y += v.y; rst.z += v.z; rst.w += v.w;
        }

        mem4.x = (mem4.x - rst.x) * betav + hcur.x * omb;
        mem4.y = (mem4.y - rst.y) * betav + hcur.y * omb;
        mem4.z = (mem4.z - rst.z) * betav + hcur.z * omb;
        mem4.w = (mem4.w - rst.w) * betav + hcur.w * omb;

        const int s[4] = {(mem4.x * invn4.x - b4.x) > 0.0f,
                          (mem4.y * invn4.y - b4.y) > 0.0f,
                          (mem4.z * invn4.z - b4.z) > 0.0f,
                          (mem4.w * invn4.w - b4.w) > 0.0f};

        float4 sv = make_float4(s[0] ? 1.f : 0.f, s[1] ? 1.f : 0.f,
                                s[2] ? 1.f : 0.f, s[3] ? 1.f : 0.f);
        *(float4*)(ob + (size_t)t * O_ + o4) = sv;
        local_count += (unsigned)(s[0] + s[1] + s[2] + s[3]);

        // ballot-aggregated appends: one LDS atomic per wave per slot
#pragma unroll
        for (int u = 0; u < 4; ++u) {
            unsigned long long mask = __ballot(s[u]);
            int base = 0;
            if (lane == 0 && mask) base = atomicAdd(&cnt[q], __popcll(mask));
            base = __shfl(base, 0, 64);
            if (s[u]) lst[q][base + __popcll(mask & below)] = o4 + u;
        }

        __syncthreads();
        hcur = hnext;
    }

    red[tid] = local_count;
    __syncthreads();
    for (int st = 128; st > 0; st >>= 1) {
        if (tid < st) red[tid] += red[tid + st];
        __syncthreads();
    }
    if (tid == 0) atomicAdd(spike_count, red[0]);
}

__global__ void finalize_loss(const unsigned int* __restrict__ spike_count,
                              float* __restrict__ loss_out) {
    *loss_out = 0.5f * ((float)(*spike_count) / 16777216.0f);
}

// ---------------------------------------------------------------------------
extern "C" void kernel_launch(void* const* d_in, const int* in_sizes, int n_in,
                              void* d_out, int out_size, void* d_ws, size_t ws_size,
                              hipStream_t stream) {
    const float* x    = (const float*)d_in[0];   // [B,T,I]
    const float* w    = (const float*)d_in[1];   // [I,O]
    const float* beta = (const float*)d_in[2];   // [1]
    const float* bias = (const float*)d_in[3];   // [O]
    float* out = (float*)d_out;                  // NOUT spikes + 1 loss

    // workspace layout (~170 MB)
    char* ws = (char*)d_ws;
    float* h    = (float*)ws;                                         // 64 MiB
    float* dmat = (float*)(ws + (size_t)67108864);                    // 4 MiB
    float* invn = (float*)(ws + (size_t)71303168);                    // 4 KiB
    unsigned int* cntp = (unsigned int*)(ws + (size_t)71307264);      // 4 KiB
    unsigned short* wt_h = (unsigned short*)(ws + (size_t)71311360);  // 2 MiB
    unsigned short* wt_m = (unsigned short*)(ws + (size_t)73408512);  // 2 MiB
    unsigned short* wt_l = (unsigned short*)(ws + (size_t)75505664);  // 2 MiB
    unsigned short* x_h  = (unsigned short*)(ws + (size_t)77602816);  // 32 MiB
    unsigned short* x_m  = (unsigned short*)(ws + (size_t)111157248); // 32 MiB
    unsigned short* x_l  = (unsigned short*)(ws + (size_t)144711680); // 32 MiB

    split_x<<<M_ * I_ / 1024, 256, 0, stream>>>(x, x_h, x_m, x_l);
    split_wt<<<dim3(I_ / 64, O_ / 64), 256, 0, stream>>>(w, wt_h, wt_m, wt_l);
    gemm_h_mfma<<<dim3(M_ / 128, O_ / 128), 256, 0, stream>>>(x_h, x_m, x_l,
                                                              wt_h, wt_m, wt_l, h);
    gemm_wtw<<<dim3(O_ / 64, O_ / 64), 256, 0, stream>>>(w, dmat);
    colnorm_diag<<<O_ / 256, 256, 0, stream>>>(dmat, invn, cntp);
    scan_kernel<<<B_, 256, 0, stream>>>(h, dmat, invn, bias, beta, out, cntp);
    finalize_loss<<<1, 1, 0, stream>>>(cntp, out + (size_t)NOUT);
}

// Round 7
// 525.405 us; speedup vs baseline: 1.7129x; 1.0241x over previous
//
#include <hip/hip_runtime.h>

#define B_ 128
#define T_ 128
#define I_ 1024
#define O_ 1024
#define M_ (B_*T_)          // 16384 rows of h
#define NOUT (M_*O_)        // 16777216 spike outputs, loss at index NOUT

typedef __attribute__((ext_vector_type(8))) short short8;   // 8 bf16 = 4 VGPR
typedef __attribute__((ext_vector_type(4))) float floatx4;  // MFMA acc

// async global->LDS, 16B per lane. LDS dest = wave-uniform base + lane*16.
__device__ __forceinline__ void gld_lds16(const void* g, void* l) {
    __builtin_amdgcn_global_load_lds((const __attribute__((address_space(1))) void*)g,
                                     (__attribute__((address_space(3))) void*)l,
                                     16, 0, 0);
}

// Workgroup barrier that waits ONLY on LDS ops (lgkmcnt(0)); does NOT drain
// vmcnt. 0xC07F = vmcnt 63 (bits 3:0 & 15:14), expcnt 7, lgkmcnt 0.
// Safe here: the inter-step protocol is LDS-only (lst/cnt); global loads are
// guarded by compiler vmcnt-before-use, global stores need no in-kernel wait.
__device__ __forceinline__ void barrier_lds_only() {
    asm volatile("" ::: "memory");
    __builtin_amdgcn_s_waitcnt(0xC07F);
    __builtin_amdgcn_s_barrier();
    asm volatile("" ::: "memory");
}

// Dekker-style exact 3-way bf16 split by truncation: x = hi + mid + lo + r,
// |r| <~ 2^-24 |x|. All subtractions exact.
__device__ __forceinline__ void split3(float x, unsigned short& h,
                                       unsigned short& m, unsigned short& l) {
    unsigned int b0 = __float_as_uint(x);
    h = (unsigned short)(b0 >> 16);
    float r1 = x - __uint_as_float(b0 & 0xFFFF0000u);
    unsigned int b1 = __float_as_uint(r1);
    m = (unsigned short)(b1 >> 16);
    float r2 = r1 - __uint_as_float(b1 & 0xFFFF0000u);
    l = (unsigned short)(__float_as_uint(r2) >> 16);
}

// ---------------------------------------------------------------------------
// split_x: x [M,K] f32 -> 3 bf16 planes, same layout. Pure memory pass.
// ---------------------------------------------------------------------------
__global__ __launch_bounds__(256) void split_x(const float* __restrict__ X,
                                               unsigned short* __restrict__ Xh,
                                               unsigned short* __restrict__ Xm,
                                               unsigned short* __restrict__ Xl) {
    size_t base = ((size_t)blockIdx.x * 256 + threadIdx.x) * 4;
    float4 v = *(const float4*)(X + base);
    ushort4 hh, mm, ll;
    split3(v.x, hh.x, mm.x, ll.x);
    split3(v.y, hh.y, mm.y, ll.y);
    split3(v.z, hh.z, mm.z, ll.z);
    split3(v.w, hh.w, mm.w, ll.w);
    *(ushort4*)(Xh + base) = hh;
    *(ushort4*)(Xm + base) = mm;
    *(ushort4*)(Xl + base) = ll;
}

// ---------------------------------------------------------------------------
// split_wt: w [K][N] f32 -> three TRANSPOSED bf16 planes wt_p[N][K].
// ---------------------------------------------------------------------------
__global__ __launch_bounds__(256) void split_wt(const float* __restrict__ W,
                                                unsigned short* __restrict__ WTh,
                                                unsigned short* __restrict__ WTm,
                                                unsigned short* __restrict__ WTl) {
    __shared__ float t[64][65];
    const int tid = threadIdx.x;
    const int tx = tid & 63, ty4 = tid >> 6;
    const int r0 = blockIdx.x * 64, c0 = blockIdx.y * 64;
#pragma unroll
    for (int j = 0; j < 16; ++j) {
        int row = j * 4 + ty4;
        t[row][tx] = W[(size_t)(r0 + row) * O_ + c0 + tx];
    }
    __syncthreads();
#pragma unroll
    for (int j = 0; j < 16; ++j) {
        int i = j * 4 + ty4;
        float v = t[tx][i];
        unsigned short h, m, l;
        split3(v, h, m, l);
        size_t off = (size_t)(c0 + i) * I_ + r0 + tx;
        WTh[off] = h; WTm[off] = m; WTl[off] = l;
    }
}

// ---------------------------------------------------------------------------
// h = x @ w, all-bf16 split MFMA. 128x128 tile, BK=32, 256 threads,
// 4 waves x (64x64), mfma_f32_16x16x32_bf16, 8 of 9 plane products.
// 6 planes in LDS (48 KB) via global_load_lds with XOR chunk swizzle
// (r6: bank conflicts 0, MfmaUtil 64%).
// ---------------------------------------------------------------------------
__global__ __launch_bounds__(256, 3) void gemm_h_mfma(
        const unsigned short* __restrict__ Xh, const unsigned short* __restrict__ Xm,
        const unsigned short* __restrict__ Xl, const unsigned short* __restrict__ WTh,
        const unsigned short* __restrict__ WTm, const unsigned short* __restrict__ WTl,
        float* __restrict__ H) {
    const int K = I_, N = O_;
    __shared__ unsigned short P[6][128 * 32];   // 6 planes x 8 KB = 48 KB

    const int tid = threadIdx.x;
    const int lane = tid & 63;
    const int wid = tid >> 6;
    const int wrow = wid >> 1, wcol = wid & 1;
    const int l15 = lane & 15, quad = lane >> 4;
    const int bm = blockIdx.x * 128, bn = blockIdx.y * 128;

    const int srow = tid >> 2, sch = tid & 3;
    const int schg = sch ^ ((srow >> 1) & 3);
    const unsigned short* gsrc[6];
    gsrc[0] = Xh  + (size_t)(bm + srow) * K + schg * 8;
    gsrc[1] = Xm  + (size_t)(bm + srow) * K + schg * 8;
    gsrc[2] = Xl  + (size_t)(bm + srow) * K + schg * 8;
    gsrc[3] = WTh + (size_t)(bn + srow) * K + schg * 8;
    gsrc[4] = WTm + (size_t)(bn + srow) * K + schg * 8;
    gsrc[5] = WTl + (size_t)(bn + srow) * K + schg * 8;

    floatx4 acc[4][4];
#pragma unroll
    for (int mt = 0; mt < 4; ++mt)
#pragma unroll
        for (int nt = 0; nt < 4; ++nt) acc[mt][nt] = (floatx4)(0.f);

    for (int kt = 0; kt < 32; ++kt) {
        const int k0 = kt * 32;
        __syncthreads();                       // all reads of P done
#pragma unroll
        for (int p = 0; p < 6; ++p) {
            unsigned short* dst = (unsigned short*)P + p * 4096 + tid * 8;
            gld_lds16(gsrc[p] + k0, dst);
            gld_lds16(gsrc[p] + (size_t)64 * K + k0, dst + 2048);
        }
        __syncthreads();                       // vmcnt drain -> LDS visible

        short8 Af[3][4];
#pragma unroll
        for (int pa = 0; pa < 3; ++pa)
#pragma unroll
            for (int mt = 0; mt < 4; ++mt) {
                int row = wrow * 64 + mt * 16 + l15;
                int chk = quad ^ ((row >> 1) & 3);
                Af[pa][mt] = *(const short8*)((const unsigned short*)P + pa * 4096 + row * 32 + chk * 8);
            }
#pragma unroll
        for (int pb = 0; pb < 3; ++pb) {
            short8 Bf[4];
#pragma unroll
            for (int nt = 0; nt < 4; ++nt) {
                int col = wcol * 64 + nt * 16 + l15;
                int chk = quad ^ ((col >> 1) & 3);
                Bf[nt] = *(const short8*)((const unsigned short*)P + (3 + pb) * 4096 + col * 32 + chk * 8);
            }
#pragma unroll
            for (int nt = 0; nt < 4; ++nt)
#pragma unroll
                for (int mt = 0; mt < 4; ++mt) {
                    acc[mt][nt] = __builtin_amdgcn_mfma_f32_16x16x32_bf16(Af[0][mt], Bf[nt], acc[mt][nt], 0, 0, 0);
                    acc[mt][nt] = __builtin_amdgcn_mfma_f32_16x16x32_bf16(Af[1][mt], Bf[nt], acc[mt][nt], 0, 0, 0);
                    if (pb < 2)
                        acc[mt][nt] = __builtin_amdgcn_mfma_f32_16x16x32_bf16(Af[2][mt], Bf[nt], acc[mt][nt], 0, 0, 0);
                }
        }
    }

    // epilogue: C/D row = quad*4 + reg, col = lane&15
#pragma unroll
    for (int mt = 0; mt < 4; ++mt)
#pragma unroll
        for (int nt = 0; nt < 4; ++nt) {
            int grow = bm + wrow * 64 + mt * 16 + quad * 4;
            int gcol = bn + wcol * 64 + nt * 16 + l15;
            float* hp = H + (size_t)grow * N + gcol;
#pragma unroll
            for (int r = 0; r < 4; ++r) hp[(size_t)r * N] = acc[mt][nt][r];
        }
}

// ---------------------------------------------------------------------------
// d = w^T w   (fp32 exact-class).
// ---------------------------------------------------------------------------
__global__ __launch_bounds__(256) void gemm_wtw(const float* __restrict__ W,
                                                float* __restrict__ D) {
    const int K = I_, N = O_;
    __shared__ float As[32][68];
    __shared__ float Bs[32][68];
    const int tid = threadIdx.x;
    const int tx = tid & 15, ty = tid >> 4;
    const int bj = blockIdx.x * 64, bo = blockIdx.y * 64;
    const int lr = tid >> 4;
    const int lc = (tid & 15) << 2;

    float acc[4][4];
#pragma unroll
    for (int m = 0; m < 4; m++)
#pragma unroll
        for (int n = 0; n < 4; n++) acc[m][n] = 0.f;

    for (int k0 = 0; k0 < K; k0 += 32) {
        float4 a0 = *(const float4*)(W + (size_t)(k0 + lr) * N + bj + lc);
        float4 a1 = *(const float4*)(W + (size_t)(k0 + lr + 16) * N + bj + lc);
        float4 b0 = *(const float4*)(W + (size_t)(k0 + lr) * N + bo + lc);
        float4 b1 = *(const float4*)(W + (size_t)(k0 + lr + 16) * N + bo + lc);
        __syncthreads();
        *(float4*)&As[lr][lc] = a0; *(float4*)&As[lr + 16][lc] = a1;
        *(float4*)&Bs[lr][lc] = b0; *(float4*)&Bs[lr + 16][lc] = b1;
        __syncthreads();
#pragma unroll
        for (int k = 0; k < 32; ++k) {
            float4 av = *(const float4*)&As[k][ty * 4];
            float4 bv = *(const float4*)&Bs[k][tx * 4];
            float am[4] = {av.x, av.y, av.z, av.w};
            float bb[4] = {bv.x, bv.y, bv.z, bv.w};
#pragma unroll
            for (int m = 0; m < 4; m++)
#pragma unroll
                for (int n = 0; n < 4; n++) acc[m][n] += am[m] * bb[n];
        }
    }
#pragma unroll
    for (int m = 0; m < 4; m++) {
        float4 v = make_float4(acc[m][0], acc[m][1], acc[m][2], acc[m][3]);
        *(float4*)(D + (size_t)(bj + ty * 4 + m) * N + bo + tx * 4) = v;
    }
}

// inv_norm[o] = 1/(d[o][o] + 1e-8); also zero the spike counter.
__global__ void colnorm_diag(const float* __restrict__ D, float* __restrict__ invn,
                             unsigned int* __restrict__ counter) {
    int o = blockIdx.x * 256 + threadIdx.x;
    if (o == 0) *counter = 0u;
    invn[o] = 1.0f / (D[(size_t)o * O_ + o] + 1e-8f);
}

// ---------------------------------------------------------------------------
// Sequential scan: one block per sample; thread owns 4 contiguous neurons.
// ONE LDS-only barrier per step:
//  - per-step count array cnt[T+1] (zeroed once) removes the read-then-zero
//    second barrier of r4-r6;
//  - barrier_lds_only() waits lgkmcnt(0) but NOT vmcnt, so spike stores /
//    h prefetches / gathers pipeline across steps instead of being drained
//    by __syncthreads' vmcnt(0) every step.
// Race-safety: a barrier every step means no wave enters step t+1 before all
// finish t; step-t appends go to lst[(t+1)&1] while step-t reads use
// lst[t&1] -> disjoint buffers between consecutive barriers.
// ---------------------------------------------------------------------------
__global__ __launch_bounds__(256) void scan_kernel(const float* __restrict__ h,
                                                   const float* __restrict__ d,
                                                   const float* __restrict__ invn,
                                                   const float* __restrict__ bias,
                                                   const float* __restrict__ beta,
                                                   float* __restrict__ out,
                                                   unsigned int* __restrict__ spike_count) {
    __shared__ int lst[2][O_];
    __shared__ int cnt[T_ + 1];
    __shared__ unsigned int red[256];

    const int tid = threadIdx.x;
    const int lane = tid & 63;
    const int b = blockIdx.x;
    const int o4 = tid * 4;
    const float betav = beta[0];
    const float omb = 1.0f - betav;

    const float4 invn4 = *(const float4*)(invn + o4);
    const float4 b4 = *(const float4*)(bias + o4);
    float4 mem4 = make_float4(0.f, 0.f, 0.f, 0.f);

    for (int i = tid; i <= T_; i += 256) cnt[i] = 0;
    unsigned int local_count = 0;
    const float* hb = h + (size_t)b * T_ * O_;
    float* ob = out + (size_t)b * T_ * O_;
    const unsigned long long below = (lane == 63) ? 0xFFFFFFFFFFFFFFFFull >> 1
                                                  : ((1ull << lane) - 1ull);

    float4 hcur = *(const float4*)(hb + o4);   // t = 0
    __syncthreads();

    for (int t = 0; t < T_; ++t) {
        const int p = t & 1, q = p ^ 1;
        const int n = cnt[t];

        float4 hnext = make_float4(0.f, 0.f, 0.f, 0.f);
        if (t + 1 < T_) hnext = *(const float4*)(hb + (size_t)(t + 1) * O_ + o4);

        float4 rst = make_float4(0.f, 0.f, 0.f, 0.f);
        int i = 0;
        for (; i + 16 <= n; i += 16) {
            float4 v[16];
#pragma unroll
            for (int u = 0; u < 16; ++u) {
                const int j = lst[p][i + u];
                v[u] = *(const float4*)(d + (size_t)j * O_ + o4);
            }
#pragma unroll
            for (int u = 0; u < 16; ++u) {
                rst.x += v[u].x; rst.y += v[u].y;
                rst.z += v[u].z; rst.w += v[u].w;
            }
        }
        for (; i + 4 <= n; i += 4) {
            float4 v[4];
#pragma unroll
            for (int u = 0; u < 4; ++u) {
                const int j = lst[p][i + u];
                v[u] = *(const float4*)(d + (size_t)j * O_ + o4);
            }
#pragma unroll
            for (int u = 0; u < 4; ++u) {
                rst.x += v[u].x; rst.y += v[u].y;
                rst.z += v[u].z; rst.w += v[u].w;
            }
        }
        for (; i < n; ++i) {
            const int j = lst[p][i];
            float4 v = *(const float4*)(d + (size_t)j * O_ + o4);
            rst.x += v.x; rst.y += v.y; rst.z += v.z; rst.w += v.w;
        }

        mem4.x = (mem4.x - rst.x) * betav + hcur.x * omb;
        mem4.y = (mem4.y - rst.y) * betav + hcur.y * omb;
        mem4.z = (mem4.z - rst.z) * betav + hcur.z * omb;
        mem4.w = (mem4.w - rst.w) * betav + hcur.w * omb;

        const int s[4] = {(mem4.x * invn4.x - b4.x) > 0.0f,
                          (mem4.y * invn4.y - b4.y) > 0.0f,
                          (mem4.z * invn4.z - b4.z) > 0.0f,
                          (mem4.w * invn4.w - b4.w) > 0.0f};

        float4 sv = make_float4(s[0] ? 1.f : 0.f, s[1] ? 1.f : 0.f,
                                s[2] ? 1.f : 0.f, s[3] ? 1.f : 0.f);
        *(float4*)(ob + (size_t)t * O_ + o4) = sv;
        local_count += (unsigned)(s[0] + s[1] + s[2] + s[3]);

        // ballot-aggregated appends into lst[q] / cnt[t+1]
#pragma unroll
        for (int u = 0; u < 4; ++u) {
            unsigned long long mask = __ballot(s[u]);
            int base = 0;
            if (lane == 0 && mask) base = atomicAdd(&cnt[t + 1], __popcll(mask));
            base = __shfl(base, 0, 64);
            if (s[u]) lst[q][base + __popcll(mask & below)] = o4 + u;
        }

        barrier_lds_only();
        hcur = hnext;
    }

    red[tid] = local_count;
    __syncthreads();
    for (int st = 128; st > 0; st >>= 1) {
        if (tid < st) red[tid] += red[tid + st];
        __syncthreads();
    }
    if (tid == 0) atomicAdd(spike_count, red[0]);
}

__global__ void finalize_loss(const unsigned int* __restrict__ spike_count,
                              float* __restrict__ loss_out) {
    *loss_out = 0.5f * ((float)(*spike_count) / 16777216.0f);
}

// ---------------------------------------------------------------------------
extern "C" void kernel_launch(void* const* d_in, const int* in_sizes, int n_in,
                              void* d_out, int out_size, void* d_ws, size_t ws_size,
                              hipStream_t stream) {
    const float* x    = (const float*)d_in[0];   // [B,T,I]
    const float* w    = (const float*)d_in[1];   // [I,O]
    const float* beta = (const float*)d_in[2];   // [1]
    const float* bias = (const float*)d_in[3];   // [O]
    float* out = (float*)d_out;                  // NOUT spikes + 1 loss

    // workspace layout (~170 MB)
    char* ws = (char*)d_ws;
    float* h    = (float*)ws;                                         // 64 MiB
    float* dmat = (float*)(ws + (size_t)67108864);                    // 4 MiB
    float* invn = (float*)(ws + (size_t)71303168);                    // 4 KiB
    unsigned int* cntp = (unsigned int*)(ws + (size_t)71307264);      // 4 KiB
    unsigned short* wt_h = (unsigned short*)(ws + (size_t)71311360);  // 2 MiB
    unsigned short* wt_m = (unsigned short*)(ws + (size_t)73408512);  // 2 MiB
    unsigned short* wt_l = (unsigned short*)(ws + (size_t)75505664);  // 2 MiB
    unsigned short* x_h  = (unsigned short*)(ws + (size_t)77602816);  // 32 MiB
    unsigned short* x_m  = (unsigned short*)(ws + (size_t)111157248); // 32 MiB
    unsigned short* x_l  = (unsigned short*)(ws + (size_t)144711680); // 32 MiB

    split_x<<<M_ * I_ / 1024, 256, 0, stream>>>(x, x_h, x_m, x_l);
    split_wt<<<dim3(I_ / 64, O_ / 64), 256, 0, stream>>>(w, wt_h, wt_m, wt_l);
    gemm_h_mfma<<<dim3(M_ / 128, O_ / 128), 256, 0, stream>>>(x_h, x_m, x_l,
                                                              wt_h, wt_m, wt_l, h);
    gemm_wtw<<<dim3(O_ / 64, O_ / 64), 256, 0, stream>>>(w, dmat);
    colnorm_diag<<<O_ / 256, 256, 0, stream>>>(dmat, invn, cntp);
    scan_kernel<<<B_, 256, 0, stream>>>(h, dmat, invn, bias, beta, out, cntp);
    finalize_loss<<<1, 1, 0, stream>>>(cntp, out + (size_t)NOUT);
}